// Round 17
// baseline (140.784 us; speedup 1.0000x reference)
//
#include <hip/hip_runtime.h>
#include <cstdint>
#include <cstddef>

typedef unsigned short u16;
typedef __attribute__((ext_vector_type(8))) short bf16x8;   // 8 bf16 = 4 VGPRs
typedef __attribute__((ext_vector_type(4))) short bf16x4;   // 4 bf16 = 2 VGPRs
typedef __attribute__((ext_vector_type(4))) float f32x4;
typedef __attribute__((ext_vector_type(16))) float f32x16;

#define B_  4
#define Q_  1024
#define K_  2048
#define E_  1024
#define H_  16
#define HD_ 64
#define LOG2E 1.4426950408889634f
#define M0_  16.0f   // fixed softmax shift (log2 domain); true max ~17, overflow only past ~95
#define NBI (B_ * K_)                   // 8192

__device__ inline u16 f2bf(float f) {
  union { float f; uint32_t u; } x; x.f = f;
  return (u16)((x.u + 0x7fffu + ((x.u >> 16) & 1u)) >> 16);  // RNE
}

// native bf16 convert — compiler emits packed cvt
__device__ inline short bfc(float f) {
  __bf16 h = (__bf16)f;
  return __builtin_bit_cast(short, h);
}

__device__ inline uint2 pack4(float4 a) {
  union { u16 u[4]; uint2 v; } r;
  r.u[0] = (u16)bfc(a.x); r.u[1] = (u16)bfc(a.y);
  r.u[2] = (u16)bfc(a.z); r.u[3] = (u16)bfc(a.w);
  return r.v;
}

__device__ inline void gload16(const u16* g, void* l) {
  __builtin_amdgcn_global_load_lds((const __attribute__((address_space(1))) void*)g,
                                   (__attribute__((address_space(3))) void*)l, 16, 0, 0);
}

// ---------------- prep: bias*log2e-M0 + 4x W[1024][1024] f32 -> Wt bf16 transpose ----------------
// Grid 1056: blocks 0..1023 transpose (z = bid>>8, xy = bid&255), 1024..1055 bias.
__global__ __launch_bounds__(256) void prep_all(const float* __restrict__ bias,
                                                const float* W0, const float* W1,
                                                const float* W2, const float* W3,
                                                float* __restrict__ bias2,
                                                u16* T0, u16* T1, u16* T2, u16* T3) {
  __shared__ float t[64][65];
  int bid = blockIdx.x;
  if (bid >= 1024) {
    int j = (bid - 1024) * 256 + threadIdx.x;
    if (j < NBI) bias2[j] = bias[j] * LOG2E - M0_;
    return;
  }
  int z = bid >> 8, xy = bid & 255;
  const float* W; u16* T;
  switch (z) {
    case 0: W = W0; T = T0; break;
    case 1: W = W1; T = T1; break;
    case 2: W = W2; T = T2; break;
    default: W = W3; T = T3; break;
  }
  int k0 = (xy & 15) * 64, n0 = (xy >> 4) * 64;
  int r = threadIdx.x >> 6, c = threadIdx.x & 63;
#pragma unroll
  for (int i = 0; i < 16; ++i)
    t[r + i * 4][c] = W[(size_t)(k0 + r + i * 4) * E_ + n0 + c];
  __syncthreads();
#pragma unroll
  for (int i = 0; i < 16; ++i)
    T[(size_t)(n0 + r + i * 4) * E_ + k0 + c] = f2bf(t[c][r + i * 4]);
}

// ---------------- bf16 GEMM body: C[M,N] = A[M,K] * Bt[N,K]^T (4-wave, 128x128) ----------------
// BK=32, 2-buffer LDS, 1 barrier/iter (r15-proven schedule). One operand may be F32:
// that operand is reg-staged (4x coalesced float4 loads at iter top, packed-cvt to bf16,
// 4x ds_write_b64 into the SAME swizzled layout after MFMA). bf16 operands use
// global_load_lds with pre-swizzled source. Chunk swizzle: physical = logical ^ ((row>>1)&3).
// LDS map (bytes): A buf0/1 @0/8192, B buf0/1 @16384/24576 (32 KiB -> 5 blocks/CU).
// MODE 1: C bf16 row-major. MODE 3: C bf16 * 0.125*log2e.
// MODE 2: C[e][n] -> vt[((n>>11)*16+(e>>6))*64+(e&63)][n&2047]
template <int MODE, bool AF32, bool BF32>
__device__ __forceinline__ void gemm_body(const void* Ap, const void* Bp,
                                          void* C, int M, int N, int Kc, int bx, int by,
                                          char* lds) {
  const int tid = threadIdx.x;
  const int w = tid >> 6, l = tid & 63;
  const int wr = w >> 1, wc = w & 1;
  const int lr = l & 15, lg = l >> 4;
  const int m0 = bx * 128, n0 = by * 128;

  // ---- bf16 gload16 staging geometry (two 16B chunks per thread) ----
  const int e0g = tid * 8, e1g = e0g + 2048;       // element offsets in 128x32 tile
  const int row0 = e0g >> 5, row1 = e1g >> 5;
  const int lc0 = ((((e0g & 31) >> 3) ^ ((row0 >> 1) & 3)) * 8);
  const int lc1 = ((((e1g & 31) >> 3) ^ ((row1 >> 1) & 3)) * 8);
  const int d0 = tid * 16, d1 = d0 + 4096;         // linear LDS dest bytes within buffer

  // ---- f32 reg-staging geometry: 4x float4 at rows fr+j*32, col fcb (128B/row coalesced) ----
  const int fr = tid >> 3;                          // 0..31
  const int fcb = (tid & 7) * 4;                    // f32 col 0..28
  const int fphys = ((fcb >> 3) ^ ((fr >> 1) & 3)); // physical 16B chunk (j-invariant)
  const int fdst = fr * 64 + fphys * 16 + (fcb & 7) * 2;  // + j*2048 bytes

  const u16* A16_0 = nullptr; const u16* A16_1 = nullptr; const float* Afp = nullptr;
  const u16* B16_0 = nullptr; const u16* B16_1 = nullptr; const float* Bfp = nullptr;
  if constexpr (AF32) {
    Afp = (const float*)Ap + (size_t)(m0 + fr) * Kc + fcb;
  } else {
    A16_0 = (const u16*)Ap + (size_t)(m0 + row0) * Kc + lc0;
    A16_1 = (const u16*)Ap + (size_t)(m0 + row1) * Kc + lc1;
  }
  if constexpr (BF32) {
    Bfp = (const float*)Bp + (size_t)(n0 + fr) * Kc + fcb;
  } else {
    B16_0 = (const u16*)Bp + (size_t)(n0 + row0) * Kc + lc0;
    B16_1 = (const u16*)Bp + (size_t)(n0 + row1) * Kc + lc1;
  }

  // ---- hoisted read offsets (bytes); chunk key constant across mt/nt ----
  const int ck = (lg ^ ((lr >> 1) & 3)) * 16;
  int aofs = (wr * 64 + lr) * 64 + ck;             // + mt*1024 imm; buffer via ^=8192
  int bofs = 16384 + (wc * 64 + lr) * 64 + ck;     // + nt*1024 imm

  f32x4 acc[4][4];
#pragma unroll
  for (int mt = 0; mt < 4; ++mt)
#pragma unroll
    for (int nt = 0; nt < 4; ++nt)
      acc[mt][nt] = (f32x4){0.f, 0.f, 0.f, 0.f};

  // ---- prologue: stage k-tile 0 -> buffer 0 ----
  if constexpr (AF32) {
    float4 t0 = *reinterpret_cast<const float4*>(Afp);
    float4 t1 = *reinterpret_cast<const float4*>(Afp + (size_t)32 * Kc);
    float4 t2 = *reinterpret_cast<const float4*>(Afp + (size_t)64 * Kc);
    float4 t3 = *reinterpret_cast<const float4*>(Afp + (size_t)96 * Kc);
    *reinterpret_cast<uint2*>(lds + fdst)        = pack4(t0);
    *reinterpret_cast<uint2*>(lds + fdst + 2048) = pack4(t1);
    *reinterpret_cast<uint2*>(lds + fdst + 4096) = pack4(t2);
    *reinterpret_cast<uint2*>(lds + fdst + 6144) = pack4(t3);
  } else {
    gload16(A16_0, lds + d0);
    gload16(A16_1, lds + d1);
  }
  if constexpr (BF32) {
    float4 t0 = *reinterpret_cast<const float4*>(Bfp);
    float4 t1 = *reinterpret_cast<const float4*>(Bfp + (size_t)32 * Kc);
    float4 t2 = *reinterpret_cast<const float4*>(Bfp + (size_t)64 * Kc);
    float4 t3 = *reinterpret_cast<const float4*>(Bfp + (size_t)96 * Kc);
    *reinterpret_cast<uint2*>(lds + 16384 + fdst)        = pack4(t0);
    *reinterpret_cast<uint2*>(lds + 16384 + fdst + 2048) = pack4(t1);
    *reinterpret_cast<uint2*>(lds + 16384 + fdst + 4096) = pack4(t2);
    *reinterpret_cast<uint2*>(lds + 16384 + fdst + 6144) = pack4(t3);
  } else {
    gload16(B16_0, lds + 16384 + d0);
    gload16(B16_1, lds + 16384 + d1);
  }
  __syncthreads();

  const int NI = Kc >> 5;                          // 32-wide k-steps
  int cur = 0;
  for (int ki = 0; ki < NI; ++ki) {
    const int nb = (cur ^ 1) * 8192;
    const bool pf = (ki + 1 < NI);
    float4 va0, va1, va2, va3, vb0, vb1, vb2, vb3;
    if (pf) {
      const int kk = (ki + 1) * 32;
      if constexpr (AF32) {
        const float* s = Afp + kk;
        va0 = *reinterpret_cast<const float4*>(s);
        va1 = *reinterpret_cast<const float4*>(s + (size_t)32 * Kc);
        va2 = *reinterpret_cast<const float4*>(s + (size_t)64 * Kc);
        va3 = *reinterpret_cast<const float4*>(s + (size_t)96 * Kc);
      } else {
        gload16(A16_0 + kk, lds + nb + d0);
        gload16(A16_1 + kk, lds + nb + d1);
      }
      if constexpr (BF32) {
        const float* s = Bfp + kk;
        vb0 = *reinterpret_cast<const float4*>(s);
        vb1 = *reinterpret_cast<const float4*>(s + (size_t)32 * Kc);
        vb2 = *reinterpret_cast<const float4*>(s + (size_t)64 * Kc);
        vb3 = *reinterpret_cast<const float4*>(s + (size_t)96 * Kc);
      } else {
        gload16(B16_0 + kk, lds + 16384 + nb + d0);
        gload16(B16_1 + kk, lds + 16384 + nb + d1);
      }
    }

    bf16x8 a[4], b[4];
#pragma unroll
    for (int mt = 0; mt < 4; ++mt)
      a[mt] = *reinterpret_cast<const bf16x8*>(lds + aofs + mt * 1024);
#pragma unroll
    for (int nt = 0; nt < 4; ++nt)
      b[nt] = *reinterpret_cast<const bf16x8*>(lds + bofs + nt * 1024);
    __builtin_amdgcn_s_setprio(1);
#pragma unroll
    for (int mt = 0; mt < 4; ++mt)
#pragma unroll
      for (int nt = 0; nt < 4; ++nt)
        acc[mt][nt] = __builtin_amdgcn_mfma_f32_16x16x32_bf16(a[mt], b[nt], acc[mt][nt], 0, 0, 0);
    __builtin_amdgcn_s_setprio(0);

    if (pf) {
      if constexpr (AF32) {
        *reinterpret_cast<uint2*>(lds + nb + fdst)        = pack4(va0);
        *reinterpret_cast<uint2*>(lds + nb + fdst + 2048) = pack4(va1);
        *reinterpret_cast<uint2*>(lds + nb + fdst + 4096) = pack4(va2);
        *reinterpret_cast<uint2*>(lds + nb + fdst + 6144) = pack4(va3);
      }
      if constexpr (BF32) {
        *reinterpret_cast<uint2*>(lds + 16384 + nb + fdst)        = pack4(vb0);
        *reinterpret_cast<uint2*>(lds + 16384 + nb + fdst + 2048) = pack4(vb1);
        *reinterpret_cast<uint2*>(lds + 16384 + nb + fdst + 4096) = pack4(vb2);
        *reinterpret_cast<uint2*>(lds + 16384 + nb + fdst + 6144) = pack4(vb3);
      }
    }

    aofs ^= 8192; bofs ^= 8192; cur ^= 1;
    __syncthreads();   // prefetch landed + this tile's LDS reads done
  }

#pragma unroll
  for (int mt = 0; mt < 4; ++mt) {
#pragma unroll
    for (int nt = 0; nt < 4; ++nt) {
      int col = n0 + wc * 64 + nt * 16 + lr;
#pragma unroll
      for (int j = 0; j < 4; ++j) {
        int row = m0 + wr * 64 + mt * 16 + lg * 4 + j;
        float v = acc[mt][nt][j];
        if (MODE == 1) {
          ((u16*)C)[(size_t)row * N + col] = f2bf(v);
        } else if (MODE == 3) {
          ((u16*)C)[(size_t)row * N + col] = f2bf(v * (0.125f * LOG2E));
        } else {
          ((u16*)C)[((size_t)((col >> 11) * 16 + (row >> 6)) * 64 + (row & 63)) * 2048 + (col & 2047)] = f2bf(v);
        }
      }
    }
  }
}

// ---------------- final GEMM: 512 threads / 8 waves (2x4), 64x32 per wave ----------------
// Triple-buffer counted-vmcnt schedule (1 load/operand/thread -> vmcnt(2)); 1 block/CU grid.
__global__ __launch_bounds__(512) void gemm_out(const u16* __restrict__ A,
                                                const u16* __restrict__ Bt,
                                                float* __restrict__ C,
                                                int N, int Kc) {
  __shared__ uint4 lds4[3072];   // 48 KiB
  char* lds = (char*)lds4;
  int d = blockIdx.x;
  int bid = (d & 7) * 32 + (d >> 3);         // XCD-chunk swizzle (256 = 8*32)
  const int bx = bid >> 3, by = bid & 7;
  const int tid = threadIdx.x;
  const int w = tid >> 6, l = tid & 63;
  const int wrow = w >> 2, wcol = w & 3;
  const int lr = l & 15, lg = l >> 4;
  const int m0 = bx * 128, n0 = by * 128;

  const int e = tid * 8;
  const int row = e >> 5;
  const int lc = ((((e & 31) >> 3) ^ ((row >> 1) & 3)) * 8);
  const u16* Ar = A  + (size_t)(m0 + row) * Kc + lc;
  const u16* Br = Bt + (size_t)(n0 + row) * Kc + lc;
  const int dd = tid * 16;

  const int ck = (lg ^ ((lr >> 1) & 3)) * 16;
  const int aofs = (wrow * 64 + lr) * 64 + ck;     // + mt*1024 imm
  const int bofs = (wcol * 32 + lr) * 64 + ck;     // + nt*1024 imm

  f32x4 acc[4][2];
#pragma unroll
  for (int mt = 0; mt < 4; ++mt)
#pragma unroll
    for (int nt = 0; nt < 2; ++nt)
      acc[mt][nt] = (f32x4){0.f, 0.f, 0.f, 0.f};

  gload16(Ar, lds + dd);
  gload16(Br, lds + 24576 + dd);
  gload16(Ar + 32, lds + 8192 + dd);
  gload16(Br + 32, lds + 24576 + 8192 + dd);
  asm volatile("s_waitcnt vmcnt(2)" ::: "memory");
  __builtin_amdgcn_s_barrier();

  const int NI = Kc >> 5;
  int rb = 0, wb = 16384;
  for (int ki = 0; ki < NI; ++ki) {
    if (ki + 2 < NI) {
      const int kk = (ki + 2) * 32;
      gload16(Ar + kk, lds + wb + dd);
      gload16(Br + kk, lds + 24576 + wb + dd);
    }

    bf16x8 a[4], b[2];
#pragma unroll
    for (int mt = 0; mt < 4; ++mt)
      a[mt] = *reinterpret_cast<const bf16x8*>(lds + rb + aofs + mt * 1024);
#pragma unroll
    for (int nt = 0; nt < 2; ++nt)
      b[nt] = *reinterpret_cast<const bf16x8*>(lds + 24576 + rb + bofs + nt * 1024);
    __builtin_amdgcn_s_setprio(1);
#pragma unroll
    for (int mt = 0; mt < 4; ++mt)
#pragma unroll
      for (int nt = 0; nt < 2; ++nt)
        acc[mt][nt] = __builtin_amdgcn_mfma_f32_16x16x32_bf16(a[mt], b[nt], acc[mt][nt], 0, 0, 0);
    __builtin_amdgcn_s_setprio(0);

    if (ki + 2 < NI) {
      asm volatile("s_waitcnt vmcnt(2)" ::: "memory");
    } else {
      asm volatile("s_waitcnt vmcnt(0)" ::: "memory");
    }
    __builtin_amdgcn_s_barrier();
    rb = (rb == 16384) ? 0 : rb + 8192;
    wb = (wb == 16384) ? 0 : wb + 8192;
  }

#pragma unroll
  for (int mt = 0; mt < 4; ++mt) {
#pragma unroll
    for (int nt = 0; nt < 2; ++nt) {
      int col = n0 + wcol * 32 + nt * 16 + lr;
#pragma unroll
      for (int j = 0; j < 4; ++j) {
        int rowc = m0 + wrow * 64 + mt * 16 + lg * 4 + j;
        C[(size_t)rowc * N + col] = acc[mt][nt][j];
      }
    }
  }
}

// ---------------- fused q/k/v projection (one dispatch, 1280 blocks) ----------------
// q-proj: A=query(f32), B=wqt. k-proj: A=memory(f32), B=wkt. v-proj: A=wvt, B=memory(f32).
// f32 operands convert-in-staging (prep pass for query/memory eliminated).
__global__ __launch_bounds__(256) void proj_fused(const float* __restrict__ query,
                                                  const float* __restrict__ memory,
                                                  const u16* __restrict__ wqt,
                                                  const u16* __restrict__ wkt,
                                                  const u16* __restrict__ wvt,
                                                  u16* __restrict__ qproj,
                                                  u16* __restrict__ kproj,
                                                  u16* __restrict__ vt) {
  __shared__ uint4 lds4[2048];   // 32 KiB -> 5 blocks/CU
  char* lds = (char*)lds4;
  int d = blockIdx.x;
  int bid = (d & 7) * 160 + (d >> 3);        // bijective: 1280 = 8*160
  if (bid < 256) {
    gemm_body<3, true, false>(query, wqt, qproj, B_ * Q_, E_, E_, bid >> 3, bid & 7, lds);
  } else if (bid < 768) {
    int i = bid - 256;
    gemm_body<1, true, false>(memory, wkt, kproj, B_ * K_, E_, E_, i >> 3, i & 7, lds);
  } else {
    int i = bid - 768;
    gemm_body<2, false, true>(wvt, memory, vt, E_, B_ * K_, E_, i & 7, i >> 3, lds);
  }
}

// ---------------- fused biased flash attention (32x32 MFMA, fixed-shift softmax) ----------------
// (unchanged — exp2 builtin, pi-permuted K, bias reg-dbuf, wk-split)
__global__ __launch_bounds__(256, 4) void attn_kernel(const u16* __restrict__ qp,
                                                      const u16* __restrict__ kp,
                                                      const u16* __restrict__ vT,
                                                      const float* __restrict__ bias2,
                                                      u16* __restrict__ out) {
  __shared__ uint4 lds4[2048];               // 32 KiB, 16B-aligned
  char* ldsb = (char*)lds4;

  const int blk = blockIdx.x;
  const int hg = blk & 63, qt = blk >> 6;     // blk%8 == h%8 -> head pinned to XCD
  const int b = hg >> 4, h = hg & 15;
  const int tid = threadIdx.x;
  const int w = tid >> 6, l = tid & 63;
  const int wq = w & 1, wk = w >> 1;
  const int l31 = l & 31, lh = l >> 5;

  // pi: swap 4-row-blocks 1<->2 and 5<->6 (so C regs hold physical k in PV order)
  const int bk4 = l31 >> 2;
  const int t4 = bk4 & 3;
  const int pk31 = (((t4 == 1) || (t4 == 2)) ? (bk4 ^ 3) : bk4) * 4 + (l31 & 3);

  // Q fragments (B-operand): lane holds Q[q=qt*64+wq*32+l31][hd=st*16+lh*8+j]
  bf16x8 qf[4];
  const u16* qrow = qp + (size_t)(b * Q_ + qt * 64 + wq * 32 + l31) * E_ + h * 64 + lh * 8;
#pragma unroll
  for (int st = 0; st < 4; ++st)
    qf[st] = *reinterpret_cast<const bf16x8*>(qrow + st * 16);

  f32x16 O0, O1;   // O^T[hd-rows][q=l31], hd-blocks 0..31 / 32..63
#pragma unroll
  for (int i = 0; i < 16; ++i) { O0[i] = 0.f; O1[i] = 0.f; }
  float OsumL = 0.f;   // per-lane partial row-sum (shfl once after the loop)

  const float* bias_b = bias2 + (size_t)b * K_;
  const u16* kbase = kp + (size_t)b * K_ * E_ + h * 64;
  const u16* vbase = vT + (size_t)(b * H_ + h) * HD_ * K_;

  // ---- hoisted LDS read offsets (bytes); buffer toggle ^=8192 ----
  const int xkk = (pk31 & 7) * 8;             // K element XOR key (pi-permuted row)
  const int xvv = (l31 & 7) * 8;              // V element XOR key
  int kofs[4];                                // K A-frag per hd-step st
#pragma unroll
  for (int st = 0; st < 4; ++st)
    kofs[st] = (wk * 32 + pk31) * 128 + (((st * 16 + lh * 8) ^ xkk) << 1);
  int vofs[2];                                // V A-frag per k-slice (+hb*4096 imm)
#pragma unroll
  for (int ksl = 0; ksl < 2; ++ksl)
    vofs[ksl] = 16384 + l31 * 128 + (((wk * 32 + ksl * 16 + lh * 8) ^ xvv) << 1);

  // ---- bias register double-buffer: current tile's 4 float4 ----
  const float* btp = bias_b + wk * 32 + lh * 8;
  float4 bg0 = *reinterpret_cast<const float4*>(btp);
  float4 bg1 = *reinterpret_cast<const float4*>(btp + 4);
  float4 bg2 = *reinterpret_cast<const float4*>(btp + 16);
  float4 bg3 = *reinterpret_cast<const float4*>(btp + 20);

  // ---- staging geometry (linear LDS dest = base + tid*16; swizzle on global SOURCE) ----
  const int e0 = tid * 8, e1 = e0 + 2048;
  const int r0 = e0 >> 6, r1 = e1 >> 6;
  const int sc0 = (e0 & 63) ^ ((r0 & 7) * 8);
  const int sc1 = (e1 & 63) ^ ((r1 & 7) * 8);
  const u16* kp0 = kbase + (size_t)r0 * E_ + sc0;
  const u16* kp1 = kbase + (size_t)r1 * E_ + sc1;
  const u16* vp0 = vbase + (size_t)r0 * K_ + sc0;
  const u16* vp1 = vbase + (size_t)r1 * K_ + sc1;

  // prologue: stage tile 0 -> buf0
  gload16(kp0, ldsb + tid * 16);
  gload16(kp1, ldsb + 4096 + tid * 16);
  gload16(vp0, ldsb + 16384 + tid * 16);
  gload16(vp1, ldsb + 16384 + 4096 + tid * 16);
  __syncthreads();

  const int NT = K_ / 64;
  for (int t = 0; t < NT; ++t) {
    // prefetch next tile direct-to-LDS (other buffer); in flight across this compute
    if (t + 1 < NT) {
      const int nb = ((t & 1) ^ 1) * 8192;   // next buffer base (bytes)
      kp0 += (size_t)64 * E_; kp1 += (size_t)64 * E_;
      vp0 += 64; vp1 += 64;
      gload16(kp0, ldsb + nb + tid * 16);
      gload16(kp1, ldsb + nb + 4096 + tid * 16);
      gload16(vp0, ldsb + 16384 + nb + tid * 16);
      gload16(vp1, ldsb + 16384 + nb + 4096 + tid * 16);
    }

    // ---- QK^T: S = K·Q^T + bias (C-init from registers), log2 domain pre-shifted ----
    f32x16 S;
    S[0] = bg0.x; S[1] = bg0.y; S[2] = bg0.z; S[3] = bg0.w;
    S[4] = bg1.x; S[5] = bg1.y; S[6] = bg1.z; S[7] = bg1.w;
    S[8] = bg2.x; S[9] = bg2.y; S[10] = bg2.z; S[11] = bg2.w;
    S[12] = bg3.x; S[13] = bg3.y; S[14] = bg3.z; S[15] = bg3.w;

    // prefetch next tile's bias into regs (consumed next iter; latency hides under MFMA)
    float4 ng0 = bg0, ng1 = bg1, ng2 = bg2, ng3 = bg3;
    if (t + 1 < NT) {
      btp += 64;
      ng0 = *reinterpret_cast<const float4*>(btp);
      ng1 = *reinterpret_cast<const float4*>(btp + 4);
      ng2 = *reinterpret_cast<const float4*>(btp + 16);
      ng3 = *reinterpret_cast<const float4*>(btp + 20);
    }

    __builtin_amdgcn_s_setprio(1);
#pragma unroll
    for (int st = 0; st < 4; ++st) {
      bf16x8 ka = *reinterpret_cast<const bf16x8*>(ldsb + kofs[st]);
      S = __builtin_amdgcn_mfma_f32_32x32x16_bf16(ka, qf[st], S, 0, 0, 0);
    }
    __builtin_amdgcn_s_setprio(0);

    // ---- P = 2^S via raw v_exp_f32 (single instr; large-negative -> 0 is wanted) ----
#pragma unroll
    for (int i = 0; i < 16; ++i) S[i] = __builtin_amdgcn_exp2f(S[i]);
    float ps = ((S[0] + S[1]) + (S[2] + S[3])) + ((S[4] + S[5]) + (S[6] + S[7]))
             + ((S[8] + S[9]) + (S[10] + S[11])) + ((S[12] + S[13]) + (S[14] + S[15]));
    OsumL += ps;

    // ---- pack P -> bf16 B-fragments (already in order thanks to pi) ----
    uint32_t u[8];
#pragma unroll
    for (int j = 0; j < 8; ++j) {
      float plo = S[2 * j], phi = S[2 * j + 1];
      asm("v_cvt_pk_bf16_f32 %0, %1, %2" : "=v"(u[j]) : "v"(plo), "v"(phi));
    }
    bf16x8 P0 = __builtin_bit_cast(bf16x8, (uint4){u[0], u[1], u[2], u[3]});
    bf16x8 P1 = __builtin_bit_cast(bf16x8, (uint4){u[4], u[5], u[6], u[7]});

    // ---- PV: O^T += V^T · P (2 hd-blocks x 2 k-slices) ----
    __builtin_amdgcn_s_setprio(1);
    {
      bf16x8 va;
      va = *reinterpret_cast<const bf16x8*>(ldsb + vofs[0]);
      O0 = __builtin_amdgcn_mfma_f32_32x32x16_bf16(va, P0, O0, 0, 0, 0);
      va = *reinterpret_cast<const bf16x8*>(ldsb + vofs[0] + 4096);
      O1 = __builtin_amdgcn_mfma_f32_32x32x16_bf16(va, P0, O1, 0, 0, 0);
      va = *reinterpret_cast<const bf16x8*>(ldsb + vofs[1]);
      O0 = __builtin_amdgcn_mfma_f32_32x32x16_bf16(va, P1, O0, 0, 0, 0);
      va = *reinterpret_cast<const bf16x8*>(ldsb + vofs[1] + 4096);
      O1 = __builtin_amdgcn_mfma_f32_32x32x16_bf16(va, P1, O1, 0, 0, 0);
    }
    __builtin_amdgcn_s_setprio(0);

    // rotate bias regs; toggle double buffer; barrier
    bg0 = ng0; bg1 = ng1; bg2 = ng2; bg3 = ng3;
    kofs[0] ^= 8192; kofs[1] ^= 8192; kofs[2] ^= 8192; kofs[3] ^= 8192;
    vofs[0] ^= 8192; vofs[1] ^= 8192;
    __syncthreads();   // prefetch landed + this tile's LDS reads done -> swap buffers
  }

  float Osum = OsumL + __shfl_xor(OsumL, 32, 64);

  // ---- cross-wave k-reduction (wk=1 -> LDS -> wk=0 adds), divide & store ----
  float* ex = (float*)ldsb + (size_t)(wq * 64 + l) * 33;
  if (wk == 1) {
#pragma unroll
    for (int i = 0; i < 16; ++i) ex[i] = O0[i];
#pragma unroll
    for (int i = 0; i < 16; ++i) ex[16 + i] = O1[i];
    ex[32] = Osum;
  }
  __syncthreads();
  if (wk == 0) {
#pragma unroll
    for (int i = 0; i < 16; ++i) O0[i] += ex[i];
#pragma unroll
    for (int i = 0; i < 16; ++i) O1[i] += ex[16 + i];
    Osum += ex[32];
    float inv = 1.f / Osum;
    u16* orow = out + (size_t)(b * Q_ + qt * 64 + wq * 32 + l31) * E_ + h * 64;
#pragma unroll
    for (int g = 0; g < 4; ++g) {
      int hd0 = 8 * g + 4 * lh;
#pragma unroll
      for (int j = 0; j < 4; ++j) {
        orow[hd0 + j] = (u16)bfc(O0[4 * g + j] * inv);
        orow[32 + hd0 + j] = (u16)bfc(O1[4 * g + j] * inv);
      }
    }
  }
}

// ---------------- launch ----------------
extern "C" void kernel_launch(void* const* d_in, const int* in_sizes, int n_in,
                              void* d_out, int out_size, void* d_ws, size_t ws_size,
                              hipStream_t stream) {
  const float* query  = (const float*)d_in[0];
  const float* memory = (const float*)d_in[1];
  const float* bias   = (const float*)d_in[2];
  const float* Wq     = (const float*)d_in[3];
  const float* Wk     = (const float*)d_in[4];
  const float* Wv     = (const float*)d_in[5];
  const float* Wo     = (const float*)d_in[6];
  float* out = (float*)d_out;

  char* p = (char*)d_ws;
  u16* wqt   = (u16*)p; p += (size_t)E_ * E_ * 2;        // 2 MiB each
  u16* wkt   = (u16*)p; p += (size_t)E_ * E_ * 2;
  u16* wvt   = (u16*)p; p += (size_t)E_ * E_ * 2;
  u16* wot   = (u16*)p; p += (size_t)E_ * E_ * 2;
  u16* qproj = (u16*)p; p += (size_t)B_ * Q_ * E_ * 2;   // 8 MiB
  u16* kproj = (u16*)p; p += (size_t)B_ * K_ * E_ * 2;   // 16 MiB
  u16* vt    = (u16*)p; p += (size_t)B_ * K_ * E_ * 2;   // 16 MiB
  u16* attn  = (u16*)p; p += (size_t)B_ * Q_ * E_ * 2;   // 8 MiB
  float* bias2 = (float*)p; p += (size_t)B_ * K_ * 4;    // 32 KiB (total ~56 MiB)

  prep_all<<<1056, 256, 0, stream>>>(bias, Wq, Wk, Wv, Wo, bias2, wqt, wkt, wvt, wot);

  proj_fused<<<1280, 256, 0, stream>>>(query, memory, wqt, wkt, wvt, qproj, kproj, vt);

  attn_kernel<<<B_ * H_ * (Q_ / 64), 256, 0, stream>>>(qproj, kproj, vt, bias2, attn);

  gemm_out<<<256, 512, 0, stream>>>(attn, wot, out, E_, E_);
}

// Round 18
// 134.799 us; speedup vs baseline: 1.0444x; 1.0444x over previous
//
#include <hip/hip_runtime.h>
#include <cstdint>
#include <cstddef>

typedef unsigned short u16;
typedef __attribute__((ext_vector_type(8))) short bf16x8;   // 8 bf16 = 4 VGPRs
typedef __attribute__((ext_vector_type(4))) short bf16x4;   // 4 bf16 = 2 VGPRs
typedef __attribute__((ext_vector_type(4))) float f32x4;
typedef __attribute__((ext_vector_type(16))) float f32x16;

#define B_  4
#define Q_  1024
#define K_  2048
#define E_  1024
#define H_  16
#define HD_ 64
#define LOG2E 1.4426950408889634f
#define M0_  16.0f   // fixed softmax shift (log2 domain); true max ~17, overflow only past ~95

__device__ inline u16 f2bf(float f) {
  union { float f; uint32_t u; } x; x.f = f;
  return (u16)((x.u + 0x7fffu + ((x.u >> 16) & 1u)) >> 16);  // RNE
}

// native bf16 convert — compiler emits packed cvt
__device__ inline short bfc(float f) {
  __bf16 h = (__bf16)f;
  return __builtin_bit_cast(short, h);
}

__device__ inline void gload16(const u16* g, void* l) {
  __builtin_amdgcn_global_load_lds((const __attribute__((address_space(1))) void*)g,
                                   (__attribute__((address_space(3))) void*)l, 16, 0, 0);
}

// ---------------- fused prep: query->bf16, memory->bf16, bias*log2e-M0, 4x W transpose ----------------
#define NQ8 (B_ * Q_ * E_ / 8)          // 524288
#define NM8 (B_ * K_ * E_ / 8)          // 1048576
#define NBI (B_ * K_)                   // 8192
#define NPREP ((NQ8 + NM8 + NBI) / 256) // 6176 exactly
__global__ __launch_bounds__(256) void prep_all(const float* __restrict__ query,
                                                const float* __restrict__ memory,
                                                const float* __restrict__ bias,
                                                const float* W0, const float* W1,
                                                const float* W2, const float* W3,
                                                u16* __restrict__ qb,
                                                u16* __restrict__ mb,
                                                float* __restrict__ bias2,
                                                u16* T0, u16* T1, u16* T2, u16* T3) {
  __shared__ float t[64][65];
  int bid = blockIdx.x;
  if (bid < NPREP) {
    int i = bid * 256 + threadIdx.x;
    const float* src;
    u16* dst;
    if (i < NQ8) {
      src = query + (size_t)i * 8; dst = qb + (size_t)i * 8;
    } else if (i < NQ8 + NM8) {
      int j = i - NQ8;
      src = memory + (size_t)j * 8; dst = mb + (size_t)j * 8;
    } else {
      int j = i - (NQ8 + NM8);
      if (j < NBI) bias2[j] = bias[j] * LOG2E - M0_;
      return;
    }
    float4 a = *reinterpret_cast<const float4*>(src);
    float4 b = *reinterpret_cast<const float4*>(src + 4);
    union { u16 u[8]; uint4 v; } r;
    r.u[0] = f2bf(a.x); r.u[1] = f2bf(a.y); r.u[2] = f2bf(a.z); r.u[3] = f2bf(a.w);
    r.u[4] = f2bf(b.x); r.u[5] = f2bf(b.y); r.u[6] = f2bf(b.z); r.u[7] = f2bf(b.w);
    *reinterpret_cast<uint4*>(dst) = r.v;
  } else {
    int tb = bid - NPREP;           // 0..1023
    int z = tb >> 8, xy = tb & 255;
    const float* W; u16* T;
    switch (z) {
      case 0: W = W0; T = T0; break;
      case 1: W = W1; T = T1; break;
      case 2: W = W2; T = T2; break;
      default: W = W3; T = T3; break;
    }
    int k0 = (xy & 15) * 64, n0 = (xy >> 4) * 64;
    int r = threadIdx.x >> 6, c = threadIdx.x & 63;
#pragma unroll
    for (int i = 0; i < 16; ++i)
      t[r + i * 4][c] = W[(size_t)(k0 + r + i * 4) * E_ + n0 + c];
    __syncthreads();
#pragma unroll
    for (int i = 0; i < 16; ++i)
      T[(size_t)(n0 + r + i * 4) * E_ + k0 + c] = f2bf(t[c][r + i * 4]);
  }
}

// ---------------- bf16 GEMM body: C[M,N] = A[M,K] * Bt[N,K]^T (4-wave, 128x128) ----------------
// BK=32, TRIPLE-buffered LDS, 2-tiles-ahead prefetch via global_load_lds, counted
// s_waitcnt vmcnt(4) + raw s_barrier (T4: newest tile's loads stay in flight across
// the barrier — never drain to 0 in the main loop).
// 16B-chunk swizzle: physical = logical ^ ((row>>1)&3), on the global SOURCE and read offset.
// LDS map (bytes): A buf0/1/2 @0/8192/16384, B buf0/1/2 @24576/32768/40960 (48 KiB).
// MODE 1: C bf16 row-major. MODE 3: C bf16 * 0.125*log2e.
// MODE 2: A=WvT[e][m], Bt=mb[n][m]; C[e][n] -> vt[((n>>11)*16+(e>>6))*64+(e&63)][n&2047]
template <int MODE>
__device__ __forceinline__ void gemm_body(const u16* __restrict__ A,
                                          const u16* __restrict__ Bt,
                                          void* __restrict__ C,
                                          int M, int N, int Kc, int bx, int by,
                                          char* lds) {
  const int tid = threadIdx.x;
  const int w = tid >> 6, l = tid & 63;
  const int wr = w >> 1, wc = w & 1;
  const int lr = l & 15, lg = l >> 4;
  const int m0 = bx * 128, n0 = by * 128;

  // ---- staging geometry: two 16B chunks per operand per thread ----
  const int e0g = tid * 8, e1g = e0g + 2048;       // element offsets in 128x32 tile
  const int row0 = e0g >> 5, row1 = e1g >> 5;
  const int lc0 = ((((e0g & 31) >> 3) ^ ((row0 >> 1) & 3)) * 8);  // logical source col
  const int lc1 = ((((e1g & 31) >> 3) ^ ((row1 >> 1) & 3)) * 8);
  const u16* Ar0 = A  + (size_t)(m0 + row0) * Kc + lc0;
  const u16* Ar1 = A  + (size_t)(m0 + row1) * Kc + lc1;
  const u16* Br0 = Bt + (size_t)(n0 + row0) * Kc + lc0;
  const u16* Br1 = Bt + (size_t)(n0 + row1) * Kc + lc1;
  const int d0 = tid * 16, d1 = d0 + 4096;         // linear LDS dest bytes within a buffer

  // ---- hoisted read offsets (bytes within buffer); chunk key constant across mt/nt ----
  const int ck = (lg ^ ((lr >> 1) & 3)) * 16;
  const int aofs = (wr * 64 + lr) * 64 + ck;       // + mt*1024 imm
  const int bofs = (wc * 64 + lr) * 64 + ck;       // + nt*1024 imm

  f32x4 acc[4][4];
#pragma unroll
  for (int mt = 0; mt < 4; ++mt)
#pragma unroll
    for (int nt = 0; nt < 4; ++nt)
      acc[mt][nt] = (f32x4){0.f, 0.f, 0.f, 0.f};

  // prologue: stage tile0 -> buf0, tile1 -> buf1; wait tile0 only (tile1 stays in flight)
  gload16(Ar0, lds + d0);
  gload16(Ar1, lds + d1);
  gload16(Br0, lds + 24576 + d0);
  gload16(Br1, lds + 24576 + d1);
  gload16(Ar0 + 32, lds + 8192 + d0);
  gload16(Ar1 + 32, lds + 8192 + d1);
  gload16(Br0 + 32, lds + 24576 + 8192 + d0);
  gload16(Br1 + 32, lds + 24576 + 8192 + d1);
  asm volatile("s_waitcnt vmcnt(4)" ::: "memory");
  __builtin_amdgcn_s_barrier();

  const int NI = Kc >> 5;                          // 32-wide k-steps
  int rb = 0, wb = 16384;                          // read/write buffer byte bases (rotate by 8192 mod 24576)
  for (int ki = 0; ki < NI; ++ki) {
    // issue tile ki+2 into wb (its last readers passed the previous barrier)
    if (ki + 2 < NI) {
      const int kk = (ki + 2) * 32;
      gload16(Ar0 + kk, lds + wb + d0);
      gload16(Ar1 + kk, lds + wb + d1);
      gload16(Br0 + kk, lds + 24576 + wb + d0);
      gload16(Br1 + kk, lds + 24576 + wb + d1);
    }

    bf16x8 a[4], b[4];
#pragma unroll
    for (int mt = 0; mt < 4; ++mt)
      a[mt] = *reinterpret_cast<const bf16x8*>(lds + rb + aofs + mt * 1024);
#pragma unroll
    for (int nt = 0; nt < 4; ++nt)
      b[nt] = *reinterpret_cast<const bf16x8*>(lds + 24576 + rb + bofs + nt * 1024);
    __builtin_amdgcn_s_setprio(1);
#pragma unroll
    for (int mt = 0; mt < 4; ++mt)
#pragma unroll
      for (int nt = 0; nt < 4; ++nt)
        acc[mt][nt] = __builtin_amdgcn_mfma_f32_16x16x32_bf16(a[mt], b[nt], acc[mt][nt], 0, 0, 0);
    __builtin_amdgcn_s_setprio(0);

    // counted wait: next tile landed; newest prefetch stays in flight across the barrier
    if (ki + 2 < NI) {
      asm volatile("s_waitcnt vmcnt(4)" ::: "memory");
    } else {
      asm volatile("s_waitcnt vmcnt(0)" ::: "memory");
    }
    __builtin_amdgcn_s_barrier();
    rb = (rb == 16384) ? 0 : rb + 8192;
    wb = (wb == 16384) ? 0 : wb + 8192;
  }

#pragma unroll
  for (int mt = 0; mt < 4; ++mt) {
#pragma unroll
    for (int nt = 0; nt < 4; ++nt) {
      int col = n0 + wc * 64 + nt * 16 + lr;
#pragma unroll
      for (int j = 0; j < 4; ++j) {
        int row = m0 + wr * 64 + mt * 16 + lg * 4 + j;
        float v = acc[mt][nt][j];
        if (MODE == 1) {
          ((u16*)C)[(size_t)row * N + col] = f2bf(v);
        } else if (MODE == 3) {
          ((u16*)C)[(size_t)row * N + col] = f2bf(v * (0.125f * LOG2E));
        } else {
          ((u16*)C)[((size_t)((col >> 11) * 16 + (row >> 6)) * 64 + (row & 63)) * 2048 + (col & 2047)] = f2bf(v);
        }
      }
    }
  }
}

// ---------------- final GEMM: 512 threads / 8 waves (2x4), 64x32 per wave ----------------
// Same triple-buffer counted-vmcnt schedule (1 load/operand/thread -> vmcnt(2)).
__global__ __launch_bounds__(512) void gemm_out(const u16* __restrict__ A,
                                                const u16* __restrict__ Bt,
                                                float* __restrict__ C,
                                                int N, int Kc) {
  __shared__ uint4 lds4[3072];   // 48 KiB
  char* lds = (char*)lds4;
  int d = blockIdx.x;
  int bid = (d & 7) * 32 + (d >> 3);         // XCD-chunk swizzle (256 = 8*32)
  const int bx = bid >> 3, by = bid & 7;
  const int tid = threadIdx.x;
  const int w = tid >> 6, l = tid & 63;
  const int wrow = w >> 2, wcol = w & 3;
  const int lr = l & 15, lg = l >> 4;
  const int m0 = bx * 128, n0 = by * 128;

  // staging: one 16B chunk per operand per thread (512 x 8 elem = 128x32 tile)
  const int e = tid * 8;
  const int row = e >> 5;
  const int lc = ((((e & 31) >> 3) ^ ((row >> 1) & 3)) * 8);
  const u16* Ar = A  + (size_t)(m0 + row) * Kc + lc;
  const u16* Br = Bt + (size_t)(n0 + row) * Kc + lc;
  const int dd = tid * 16;

  const int ck = (lg ^ ((lr >> 1) & 3)) * 16;
  const int aofs = (wrow * 64 + lr) * 64 + ck;     // + mt*1024 imm
  const int bofs = (wcol * 32 + lr) * 64 + ck;     // + nt*1024 imm

  f32x4 acc[4][2];
#pragma unroll
  for (int mt = 0; mt < 4; ++mt)
#pragma unroll
    for (int nt = 0; nt < 2; ++nt)
      acc[mt][nt] = (f32x4){0.f, 0.f, 0.f, 0.f};

  gload16(Ar, lds + dd);
  gload16(Br, lds + 24576 + dd);
  gload16(Ar + 32, lds + 8192 + dd);
  gload16(Br + 32, lds + 24576 + 8192 + dd);
  asm volatile("s_waitcnt vmcnt(2)" ::: "memory");
  __builtin_amdgcn_s_barrier();

  const int NI = Kc >> 5;
  int rb = 0, wb = 16384;
  for (int ki = 0; ki < NI; ++ki) {
    if (ki + 2 < NI) {
      const int kk = (ki + 2) * 32;
      gload16(Ar + kk, lds + wb + dd);
      gload16(Br + kk, lds + 24576 + wb + dd);
    }

    bf16x8 a[4], b[2];
#pragma unroll
    for (int mt = 0; mt < 4; ++mt)
      a[mt] = *reinterpret_cast<const bf16x8*>(lds + rb + aofs + mt * 1024);
#pragma unroll
    for (int nt = 0; nt < 2; ++nt)
      b[nt] = *reinterpret_cast<const bf16x8*>(lds + 24576 + rb + bofs + nt * 1024);
    __builtin_amdgcn_s_setprio(1);
#pragma unroll
    for (int mt = 0; mt < 4; ++mt)
#pragma unroll
      for (int nt = 0; nt < 2; ++nt)
        acc[mt][nt] = __builtin_amdgcn_mfma_f32_16x16x32_bf16(a[mt], b[nt], acc[mt][nt], 0, 0, 0);
    __builtin_amdgcn_s_setprio(0);

    if (ki + 2 < NI) {
      asm volatile("s_waitcnt vmcnt(2)" ::: "memory");
    } else {
      asm volatile("s_waitcnt vmcnt(0)" ::: "memory");
    }
    __builtin_amdgcn_s_barrier();
    rb = (rb == 16384) ? 0 : rb + 8192;
    wb = (wb == 16384) ? 0 : wb + 8192;
  }

#pragma unroll
  for (int mt = 0; mt < 4; ++mt) {
#pragma unroll
    for (int nt = 0; nt < 2; ++nt) {
      int col = n0 + wcol * 32 + nt * 16 + lr;
#pragma unroll
      for (int j = 0; j < 4; ++j) {
        int rowc = m0 + wrow * 64 + mt * 16 + lg * 4 + j;
        C[(size_t)rowc * N + col] = acc[mt][nt][j];
      }
    }
  }
}

// ---------------- fused q/k/v projection (one dispatch, 1280 blocks) ----------------
__global__ __launch_bounds__(256) void proj_fused(const u16* __restrict__ qb,
                                                  const u16* __restrict__ mb,
                                                  const u16* __restrict__ wqt,
                                                  const u16* __restrict__ wkt,
                                                  const u16* __restrict__ wvt,
                                                  u16* __restrict__ qproj,
                                                  u16* __restrict__ kproj,
                                                  u16* __restrict__ vt) {
  __shared__ uint4 lds4[3072];   // 48 KiB -> 3 blocks/CU
  char* lds = (char*)lds4;
  int d = blockIdx.x;
  int bid = (d & 7) * 160 + (d >> 3);        // bijective: 1280 = 8*160
  if (bid < 256) {
    gemm_body<3>(qb, wqt, qproj, B_ * Q_, E_, E_, bid >> 3, bid & 7, lds);
  } else if (bid < 768) {
    int i = bid - 256;
    gemm_body<1>(mb, wkt, kproj, B_ * K_, E_, E_, i >> 3, i & 7, lds);
  } else {
    int i = bid - 768;
    gemm_body<2>(wvt, mb, vt, E_, B_ * K_, E_, i & 7, i >> 3, lds);
  }
}

// ---------------- fused biased flash attention (32x32 MFMA, fixed-shift softmax) ----------------
// (exp2 builtin, pi-permuted K, bias reg-dbuf, wk-split)
__global__ __launch_bounds__(256, 4) void attn_kernel(const u16* __restrict__ qp,
                                                      const u16* __restrict__ kp,
                                                      const u16* __restrict__ vT,
                                                      const float* __restrict__ bias2,
                                                      u16* __restrict__ out) {
  __shared__ uint4 lds4[2048];               // 32 KiB, 16B-aligned
  char* ldsb = (char*)lds4;

  const int blk = blockIdx.x;
  const int hg = blk & 63, qt = blk >> 6;     // blk%8 == h%8 -> head pinned to XCD
  const int b = hg >> 4, h = hg & 15;
  const int tid = threadIdx.x;
  const int w = tid >> 6, l = tid & 63;
  const int wq = w & 1, wk = w >> 1;
  const int l31 = l & 31, lh = l >> 5;

  // pi: swap 4-row-blocks 1<->2 and 5<->6 (so C regs hold physical k in PV order)
  const int bk4 = l31 >> 2;
  const int t4 = bk4 & 3;
  const int pk31 = (((t4 == 1) || (t4 == 2)) ? (bk4 ^ 3) : bk4) * 4 + (l31 & 3);

  // Q fragments (B-operand): lane holds Q[q=qt*64+wq*32+l31][hd=st*16+lh*8+j]
  bf16x8 qf[4];
  const u16* qrow = qp + (size_t)(b * Q_ + qt * 64 + wq * 32 + l31) * E_ + h * 64 + lh * 8;
#pragma unroll
  for (int st = 0; st < 4; ++st)
    qf[st] = *reinterpret_cast<const bf16x8*>(qrow + st * 16);

  f32x16 O0, O1;   // O^T[hd-rows][q=l31], hd-blocks 0..31 / 32..63
#pragma unroll
  for (int i = 0; i < 16; ++i) { O0[i] = 0.f; O1[i] = 0.f; }
  float OsumL = 0.f;   // per-lane partial row-sum (shfl once after the loop)

  const float* bias_b = bias2 + (size_t)b * K_;
  const u16* kbase = kp + (size_t)b * K_ * E_ + h * 64;
  const u16* vbase = vT + (size_t)(b * H_ + h) * HD_ * K_;

  // ---- hoisted LDS read offsets (bytes); buffer toggle ^=8192 ----
  const int xkk = (pk31 & 7) * 8;             // K element XOR key (pi-permuted row)
  const int xvv = (l31 & 7) * 8;              // V element XOR key
  int kofs[4];                                // K A-frag per hd-step st
#pragma unroll
  for (int st = 0; st < 4; ++st)
    kofs[st] = (wk * 32 + pk31) * 128 + (((st * 16 + lh * 8) ^ xkk) << 1);
  int vofs[2];                                // V A-frag per k-slice (+hb*4096 imm)
#pragma unroll
  for (int ksl = 0; ksl < 2; ++ksl)
    vofs[ksl] = 16384 + l31 * 128 + (((wk * 32 + ksl * 16 + lh * 8) ^ xvv) << 1);

  // ---- bias register double-buffer: current tile's 4 float4 ----
  const float* btp = bias_b + wk * 32 + lh * 8;
  float4 bg0 = *reinterpret_cast<const float4*>(btp);
  float4 bg1 = *reinterpret_cast<const float4*>(btp + 4);
  float4 bg2 = *reinterpret_cast<const float4*>(btp + 16);
  float4 bg3 = *reinterpret_cast<const float4*>(btp + 20);

  // ---- staging geometry (linear LDS dest = base + tid*16; swizzle on global SOURCE) ----
  const int e0 = tid * 8, e1 = e0 + 2048;
  const int r0 = e0 >> 6, r1 = e1 >> 6;
  const int sc0 = (e0 & 63) ^ ((r0 & 7) * 8);
  const int sc1 = (e1 & 63) ^ ((r1 & 7) * 8);
  const u16* kp0 = kbase + (size_t)r0 * E_ + sc0;
  const u16* kp1 = kbase + (size_t)r1 * E_ + sc1;
  const u16* vp0 = vbase + (size_t)r0 * K_ + sc0;
  const u16* vp1 = vbase + (size_t)r1 * K_ + sc1;

  // prologue: stage tile 0 -> buf0
  gload16(kp0, ldsb + tid * 16);
  gload16(kp1, ldsb + 4096 + tid * 16);
  gload16(vp0, ldsb + 16384 + tid * 16);
  gload16(vp1, ldsb + 16384 + 4096 + tid * 16);
  __syncthreads();

  const int NT = K_ / 64;
  for (int t = 0; t < NT; ++t) {
    // prefetch next tile direct-to-LDS (other buffer); in flight across this compute
    if (t + 1 < NT) {
      const int nb = ((t & 1) ^ 1) * 8192;   // next buffer base (bytes)
      kp0 += (size_t)64 * E_; kp1 += (size_t)64 * E_;
      vp0 += 64; vp1 += 64;
      gload16(kp0, ldsb + nb + tid * 16);
      gload16(kp1, ldsb + nb + 4096 + tid * 16);
      gload16(vp0, ldsb + 16384 + nb + tid * 16);
      gload16(vp1, ldsb + 16384 + nb + 4096 + tid * 16);
    }

    // ---- QK^T: S = K·Q^T + bias (C-init from registers), log2 domain pre-shifted ----
    f32x16 S;
    S[0] = bg0.x; S[1] = bg0.y; S[2] = bg0.z; S[3] = bg0.w;
    S[4] = bg1.x; S[5] = bg1.y; S[6] = bg1.z; S[7] = bg1.w;
    S[8] = bg2.x; S[9] = bg2.y; S[10] = bg2.z; S[11] = bg2.w;
    S[12] = bg3.x; S[13] = bg3.y; S[14] = bg3.z; S[15] = bg3.w;

    // prefetch next tile's bias into regs (consumed next iter; latency hides under MFMA)
    float4 ng0 = bg0, ng1 = bg1, ng2 = bg2, ng3 = bg3;
    if (t + 1 < NT) {
      btp += 64;
      ng0 = *reinterpret_cast<const float4*>(btp);
      ng1 = *reinterpret_cast<const float4*>(btp + 4);
      ng2 = *reinterpret_cast<const float4*>(btp + 16);
      ng3 = *reinterpret_cast<const float4*>(btp + 20);
    }

    __builtin_amdgcn_s_setprio(1);
#pragma unroll
    for (int st = 0; st < 4; ++st) {
      bf16x8 ka = *reinterpret_cast<const bf16x8*>(ldsb + kofs[st]);
      S = __builtin_amdgcn_mfma_f32_32x32x16_bf16(ka, qf[st], S, 0, 0, 0);
    }
    __builtin_amdgcn_s_setprio(0);

    // ---- P = 2^S via raw v_exp_f32 (single instr; large-negative -> 0 is wanted) ----
#pragma unroll
    for (int i = 0; i < 16; ++i) S[i] = __builtin_amdgcn_exp2f(S[i]);
    float ps = ((S[0] + S[1]) + (S[2] + S[3])) + ((S[4] + S[5]) + (S[6] + S[7]))
             + ((S[8] + S[9]) + (S[10] + S[11])) + ((S[12] + S[13]) + (S[14] + S[15]));
    OsumL += ps;

    // ---- pack P -> bf16 B-fragments (already in order thanks to pi) ----
    uint32_t u[8];
#pragma unroll
    for (int j = 0; j < 8; ++j) {
      float plo = S[2 * j], phi = S[2 * j + 1];
      asm("v_cvt_pk_bf16_f32 %0, %1, %2" : "=v"(u[j]) : "v"(plo), "v"(phi));
    }
    bf16x8 P0 = __builtin_bit_cast(bf16x8, (uint4){u[0], u[1], u[2], u[3]});
    bf16x8 P1 = __builtin_bit_cast(bf16x8, (uint4){u[4], u[5], u[6], u[7]});

    // ---- PV: O^T += V^T · P (2 hd-blocks x 2 k-slices) ----
    __builtin_amdgcn_s_setprio(1);
    {
      bf16x8 va;
      va = *reinterpret_cast<const bf16x8*>(ldsb + vofs[0]);
      O0 = __builtin_amdgcn_mfma_f32_32x32x16_bf16(va, P0, O0, 0, 0, 0);
      va = *reinterpret_cast<const bf16x8*>(ldsb + vofs[0] + 4096);
      O1 = __builtin_amdgcn_mfma_f32_32x32x16_bf16(va, P0, O1, 0, 0, 0);
      va = *reinterpret_cast<const bf16x8*>(ldsb + vofs[1]);
      O0 = __builtin_amdgcn_mfma_f32_32x32x16_bf16(va, P1, O0, 0, 0, 0);
      va = *reinterpret_cast<const bf16x8*>(ldsb + vofs[1] + 4096);
      O1 = __builtin_amdgcn_mfma_f32_32x32x16_bf16(va, P1, O1, 0, 0, 0);
    }
    __builtin_amdgcn_s_setprio(0);

    // rotate bias regs; toggle double buffer; barrier
    bg0 = ng0; bg1 = ng1; bg2 = ng2; bg3 = ng3;
    kofs[0] ^= 8192; kofs[1] ^= 8192; kofs[2] ^= 8192; kofs[3] ^= 8192;
    vofs[0] ^= 8192; vofs[1] ^= 8192;
    __syncthreads();   // prefetch landed + this tile's LDS reads done -> swap buffers
  }

  float Osum = OsumL + __shfl_xor(OsumL, 32, 64);

  // ---- cross-wave k-reduction (wk=1 -> LDS -> wk=0 adds), divide & store ----
  float* ex = (float*)ldsb + (size_t)(wq * 64 + l) * 33;
  if (wk == 1) {
#pragma unroll
    for (int i = 0; i < 16; ++i) ex[i] = O0[i];
#pragma unroll
    for (int i = 0; i < 16; ++i) ex[16 + i] = O1[i];
    ex[32] = Osum;
  }
  __syncthreads();
  if (wk == 0) {
#pragma unroll
    for (int i = 0; i < 16; ++i) O0[i] += ex[i];
#pragma unroll
    for (int i = 0; i < 16; ++i) O1[i] += ex[16 + i];
    Osum += ex[32];
    float inv = 1.f / Osum;
    u16* orow = out + (size_t)(b * Q_ + qt * 64 + wq * 32 + l31) * E_ + h * 64;
#pragma unroll
    for (int g = 0; g < 4; ++g) {
      int hd0 = 8 * g + 4 * lh;
#pragma unroll
      for (int j = 0; j < 4; ++j) {
        orow[hd0 + j] = (u16)bfc(O0[4 * g + j] * inv);
        orow[32 + hd0 + j] = (u16)bfc(O1[4 * g + j] * inv);
      }
    }
  }
}

// ---------------- launch ----------------
extern "C" void kernel_launch(void* const* d_in, const int* in_sizes, int n_in,
                              void* d_out, int out_size, void* d_ws, size_t ws_size,
                              hipStream_t stream) {
  const float* query  = (const float*)d_in[0];
  const float* memory = (const float*)d_in[1];
  const float* bias   = (const float*)d_in[2];
  const float* Wq     = (const float*)d_in[3];
  const float* Wk     = (const float*)d_in[4];
  const float* Wv     = (const float*)d_in[5];
  const float* Wo     = (const float*)d_in[6];
  float* out = (float*)d_out;

  char* p = (char*)d_ws;
  u16* qb    = (u16*)p; p += (size_t)B_ * Q_ * E_ * 2;   // 8 MiB
  u16* mb    = (u16*)p; p += (size_t)B_ * K_ * E_ * 2;   // 16 MiB
  u16* wqt   = (u16*)p; p += (size_t)E_ * E_ * 2;        // 2 MiB
  u16* wkt   = (u16*)p; p += (size_t)E_ * E_ * 2;
  u16* wvt   = (u16*)p; p += (size_t)E_ * E_ * 2;
  u16* wot   = (u16*)p; p += (size_t)E_ * E_ * 2;
  u16* qproj = (u16*)p; p += (size_t)B_ * Q_ * E_ * 2;   // 8 MiB
  u16* kproj = (u16*)p; p += (size_t)B_ * K_ * E_ * 2;   // 16 MiB
  u16* vt    = (u16*)p; p += (size_t)B_ * K_ * E_ * 2;   // 16 MiB
  u16* attn  = (u16*)p; p += (size_t)B_ * Q_ * E_ * 2;   // 8 MiB
  float* bias2 = (float*)p; p += (size_t)B_ * K_ * 4;    // 32 KiB (total ~80 MiB)

  prep_all<<<NPREP + 1024, 256, 0, stream>>>(query, memory, bias, Wq, Wk, Wv, Wo,
                                             qb, mb, bias2, wqt, wkt, wvt, wot);

  proj_fused<<<1280, 256, 0, stream>>>(qb, mb, wqt, wkt, wvt, qproj, kproj, vt);

  attn_kernel<<<B_ * H_ * (Q_ / 64), 256, 0, stream>>>(qproj, kproj, vt, bias2, attn);

  gemm_out<<<256, 512, 0, stream>>>(attn, wot, out, E_, E_);
}